// Round 10
// baseline (346.283 us; speedup 1.0000x reference)
//
#include <hip/hip_runtime.h>
#include <hip/hip_bf16.h>

// Problem constants (all powers of two -> index math is shifts/masks)
#define B_   8
#define N_   16384
#define C_   128
#define OUT_ 256
#define E_   262144

// ws word layout (uint32 offsets). ws_size ~537 MB, we use ~40 MB.
//   [0,        16384)    : cnt[row]; memset 0 -> per-row edge count (may exceed 64)
//   [16384,    16448)    : ovf_cnt (word 16384) + pad; memset covers it
//   [16448,    540736)   : overflow (row,col) pairs - correctness path only
//   [540736,   1589312)  : tab: fixed-capacity col table, 64 slots/row (16384*64)
//   [1589312,  1605696)  : Wt bf16 [n][k] transposed weights (256x128)
//   [1605696,  9994304)  : x_bf bf16 copy of x (B*N*C shorts)
#define CNT_OFF  0u
#define OVFC_OFF 16384u
#define OVF_OFF  16448u
#define TAB_OFF  540736u
#define WT_OFF   1589312u
#define XBF_OFF  1605696u

typedef __attribute__((ext_vector_type(8))) short bf16x8; // 8 bf16 = 4 VGPRs
typedef __attribute__((ext_vector_type(4))) float f32x4;

__device__ __forceinline__ unsigned short f2bf(float f) { // RNE, no NaN inputs
  unsigned u = __float_as_uint(f);
  u += 0x7FFFu + ((u >> 16) & 1u);
  return (unsigned short)(u >> 16);
}
// R10: fast GELU. erff is a branchy ~40-op libm path (R9 theory: 64 calls/lane
// made k_ag VALU-bound). tanh-form via hw exp2 + v_rcp = ~12 ops, 2 on the
// trans pipe. |err| vs exact GELU <~2e-3 << 4.03e-2 threshold.
__device__ __forceinline__ float gelu_fast(float x) {
  float x2 = x * x;
  float inner = fmaf(0.0356774081f, x2, 0.7978845608f); // sqrt(2/pi)*(1+0.044715x^2)
  float y2l = fminf(x * inner * 2.8853900818f, 126.0f); // 2y*log2(e), ovf-clamped
  float z = exp2f(y2l);                                 // e^{2y}, hw v_exp_f32
  float t = (z - 1.0f) * __builtin_amdgcn_rcpf(z + 1.0f); // tanh(y)
  float h = 0.5f * x;
  return fmaf(h, t, h); // 0.5x(1+tanh(y))
}
__device__ __forceinline__ unsigned umin_(unsigned a, unsigned b) {
  return a < b ? a : b;
}

// ------------- kernel 1: fused x->bf16 | direct edge-table build | Wt prep ------
// Fixed-capacity table (64 slots/row) built in ONE edge pass with atomic cursors
// (the gather needs the col SET, not order). Overflow rows (P ~ 1e-14 at
// Poisson(16)) spill (row,col) pairs to a global list replayed later -> correct
// for ANY input. Per-block dtype detect: odd u32 words are int64-highs (==0) or
// int32 index values (nonzero w.h.p.); 256 samples/block -> P(wrong) ~ 0.
__global__ __launch_bounds__(256) void k_prep(const float* __restrict__ x,
                                              const unsigned* __restrict__ eidx,
                                              const float* __restrict__ W,
                                              unsigned* __restrict__ ws) {
  const unsigned bid = blockIdx.x, tid = threadIdx.x;
  if (bid < 16384u) { // ---- x fp32 -> bf16 packed (4,194,304 float4 slots)
    unsigned i = bid * 256u + tid;
    float4 v = ((const float4*)x)[i];
    uint2 o;
    o.x = (unsigned)f2bf(v.x) | ((unsigned)f2bf(v.y) << 16);
    o.y = (unsigned)f2bf(v.z) | ((unsigned)f2bf(v.w) << 16);
    ((uint2*)(ws + XBF_OFF))[i] = o;
  } else if (bid < 17408u) { // ---- edge-table build, one edge per thread
    __shared__ int flag32;
    if (tid == 0) flag32 = 0;
    __syncthreads();
    unsigned e = (bid - 16384u) * 256u + tid; // 0..262143
    if (eidx[2u * e + 1u] != 0u) flag32 = 1;  // benign race
    __syncthreads();
    int row, col;
    if (flag32) {
      row = (int)eidx[e];
      col = (int)eidx[e + E_];
    } else {
      const long long* p = (const long long*)eidx;
      row = (int)p[e];
      col = (int)p[e + E_];
    }
    unsigned pos = atomicAdd(ws + CNT_OFF + (unsigned)row, 1u);
    if (pos < 64u) {
      ws[TAB_OFF + ((unsigned)row << 6) + pos] = (unsigned)col;
    } else { // correctness-only spill
      unsigned o = atomicAdd(ws + OVFC_OFF, 1u);
      ws[OVF_OFF + 2u * o]      = (unsigned)row;
      ws[OVF_OFF + 2u * o + 1u] = (unsigned)col;
    }
  } else { // ---- W fp32 -> bf16 transposed (128 blocks)
    unsigned t = (bid - 17408u) * 256u + tid; // 0..32767
    unsigned n = t >> 7, k = t & 127u;
    ((unsigned short*)(ws + WT_OFF))[n * 128u + k] = f2bf(W[k * 256u + n]);
  }
}

// -------- kernel 2: FUSED gather-max -> (LDS transpose) -> MFMA gemm -> GELU ----
// R9 counters: VGPR=44 + ~40 MB spill (WRITE 174 vs out 134) -> phase 1's
// 2-row live state (~60-70 regs) exceeds every allocation the compiler picks.
// R10: phase 1 processes ONE row/iter (live ~35 regs -> spill-free at 44+),
// with per-k wave-uniform load skip (no redundant clamped loads except the
// last group). gelu_fast replaces erff (R9 theory: 64 erff/lane = VALU hog).
// Kept (proven): (256,4) bound; 17408 B LDS (Wt n-quarters); nt OUT stores +
// nt TAB loads (FETCH 155->48 MB, R7); cnt16 hoist; clamp trick (max idempotent).
// EXEC discipline (R1 bug): every __shfl under wave-uniform control flow.
// Max trick: fmax on raw u32 (hi channel; garbage low mantissa can't flip a
// bf16-level compare) and on u<<16 (lo channel, exact). batch = blockIdx&7 ->
// per-XCD 4 MB x_bf slice under round-robin dispatch.
__global__ __launch_bounds__(256, 4) void k_ag(const uint4* __restrict__ xbf4,
                                               const unsigned* __restrict__ ws,
                                               const unsigned short* __restrict__ Wt,
                                               const float* __restrict__ bias,
                                               float* __restrict__ out) {
  __shared__ unsigned short sm[8704]; // 17408 B: 4 trans strips / one Wt quarter
  const unsigned bi = blockIdx.x;          // 2048 = 256 m-tiles x 8 batches
  const unsigned b  = bi & 7u;
  const unsigned mbase = (bi >> 3) << 6;   // 64-row m-tile
  const unsigned tid = threadIdx.x;
  const unsigned wv = tid >> 6;            // wave id: rows [wv*16, wv*16+16)
  const unsigned lane = tid & 63u;
  const unsigned g  = lane >> 4;           // edge subgroup 0..3
  const unsigned ln = lane & 15u;          // uint4 slot within a 128-ch row
  const uint4* xb = xbf4 + ((size_t)b << 18); // rows stride 16 uint4
  const unsigned wbase = mbase + (wv << 4);

  // one load covers all 16 row degrees for this wave (lanes 16+ hold dups)
  const unsigned cnt16 = ws[CNT_OFF + wbase + ln];
  const unsigned novf  = ws[OVFC_OFF]; // overflow count (0 in practice)

#define MAXU4(U, ml, mh)                                                    \
  mh[0] = fmaxf(mh[0], __uint_as_float((U).x));                             \
  ml[0] = fmaxf(ml[0], __uint_as_float((U).x << 16));                       \
  mh[1] = fmaxf(mh[1], __uint_as_float((U).y));                             \
  ml[1] = fmaxf(ml[1], __uint_as_float((U).y << 16));                       \
  mh[2] = fmaxf(mh[2], __uint_as_float((U).z));                             \
  ml[2] = fmaxf(ml[2], __uint_as_float((U).z << 16));                       \
  mh[3] = fmaxf(mh[3], __uint_as_float((U).w));                             \
  ml[3] = fmaxf(ml[3], __uint_as_float((U).w << 16));

  // ---- phase 1: gather-max, ONE row per iteration (low live state) ----
  for (unsigned i = 0u; i < 16u; ++i) {
    const unsigned row = wbase + i;
    const unsigned deg = (unsigned)__shfl((int)cnt16, (int)i); // wave-uniform
    const unsigned d64 = deg < 64u ? deg : 64u;

    float mlo[4], mhi[4];
#pragma unroll
    for (int r = 0; r < 4; ++r) { mlo[r] = -INFINITY; mhi[r] = -INFINITY; }

    if (deg) { // wave-uniform
      const unsigned dm1 = d64 - 1u;
      // tab: read-once stream shared by all XCDs -> nt (L3 serves it)
      const unsigned cpre =
          __builtin_nontemporal_load(ws + TAB_OFF + (row << 6) + lane);
      for (unsigned t = 0u; t < d64; t += 16u) {
#pragma unroll
        for (int k = 0; k < 4; ++k) {
          if (t + 4u * (unsigned)k < d64) { // wave-uniform skip: no redundant grp
            unsigned c = (unsigned)__shfl(
                (int)cpre, (int)umin_(t + 4u * (unsigned)k + g, dm1));
            uint4 u = xb[((size_t)c << 4) + ln];
            MAXU4(u, mlo, mhi)
          }
        }
      }
      if (deg > 64u) { // overflow replay: correctness-only, shuffle-free
        for (unsigned k2 = g; k2 < novf; k2 += 4u) {
          if (__builtin_nontemporal_load(ws + OVF_OFF + 2u * k2) == row) {
            uint4 u = xb[((size_t)ws[OVF_OFF + 2u * k2 + 1u] << 4) + ln];
            MAXU4(u, mlo, mhi)
          }
        }
      }
    }

    // own-row x issued here: latency overlaps the reduce shuffles below
    const uint4 xw = xb[((size_t)row << 4) + ln];

    // reduce across the 4 edge-groups (full EXEC, reconverged)
#pragma unroll
    for (int r = 0; r < 4; ++r) {
      mlo[r] = fmaxf(mlo[r], __shfl_xor(mlo[r], 16, 64));
      mhi[r] = fmaxf(mhi[r], __shfl_xor(mhi[r], 16, 64));
      mlo[r] = fmaxf(mlo[r], __shfl_xor(mlo[r], 32, 64));
      mhi[r] = fmaxf(mhi[r], __shfl_xor(mhi[r], 32, 64));
    }

    if (g == 0u) { // write this row's aggr bf16 to this wave's LDS strip
      const bool has = (deg != 0u);
      unsigned xv[4] = {xw.x, xw.y, xw.z, xw.w};
      unsigned ox[4];
#pragma unroll
      for (int r = 0; r < 4; ++r) {
        float vlo = has ? mlo[r] : 0.0f;
        float vhi = has ? __uint_as_float(__float_as_uint(mhi[r]) & 0xFFFF0000u)
                        : 0.0f;
        ox[r] = (unsigned)f2bf(vlo - __uint_as_float(xv[r] << 16)) |
                ((unsigned)f2bf(vhi - __uint_as_float(xv[r] & 0xFFFF0000u)) << 16);
      }
      uint4 o = {ox[0], ox[1], ox[2], ox[3]};
      *(uint4*)&sm[wv * 2176u + i * 136u + ln * 8u] = o;
    }
  }
#undef MAXU4

  __syncthreads(); // trans strips complete (also orders vs af reads)

  // ---- phase 2: A-fragments from LDS. lane(ln,q): A[m=ln][ch=kc*32+q*8..+8]
  const unsigned q = g;
  bf16x8 af[4];
#pragma unroll
  for (int kc = 0; kc < 4; ++kc)
    af[kc] = *(const bf16x8*)&sm[wv * 2176u + ln * 136u + (unsigned)kc * 32u + q * 8u];
  __syncthreads(); // af reads drained before Wt overwrites sm

  // ---- phase 3: per n-quarter: stage Wt (16 KB), MFMA, bias + GELU, nt-store --
#pragma unroll
  for (int qt = 0; qt < 4; ++qt) {
    const int nbase = qt * 64;
#pragma unroll
    for (int i2 = 0; i2 < 4; ++i2) {
      int slot = i2 * 256 + (int)tid; // 0..1023 = 64 rows x 16 k-units
      int n = slot >> 4, k8 = slot & 15;
      uint4 u = *(const uint4*)(Wt + (size_t)(nbase + n) * 128 + k8 * 8);
      *(uint4*)&sm[n * 136 + k8 * 8] = u;
    }
    __syncthreads();

    f32x4 acc[4];
#pragma unroll
    for (int f = 0; f < 4; ++f) acc[f] = (f32x4){0.f, 0.f, 0.f, 0.f};
#pragma unroll
    for (int kc = 0; kc < 4; ++kc) {
#pragma unroll
      for (int f = 0; f < 4; ++f) {
        // B[k=q*8+j][n=f*16+ln] contiguous in Wt[n][k]
        bf16x8 bf = *(const bf16x8*)&sm[(f * 16 + (int)ln) * 136 + kc * 32 + (int)q * 8];
        acc[f] = __builtin_amdgcn_mfma_f32_16x16x32_bf16(af[kc], bf, acc[f], 0, 0, 0);
      }
    }

    // Epilogue: C/D layout col = lane&15, row = quad*4 + reg (m89-verified).
    // out is write-once -> nontemporal (don't evict the x_bf gather set).
#pragma unroll
    for (int f = 0; f < 4; ++f) {
      int n = nbase + f * 16 + (int)ln;
      float bv = bias[n];
#pragma unroll
      for (int r = 0; r < 4; ++r) {
        size_t mrow = ((size_t)b << 14) + mbase + (wv << 4) + q * 4u + (unsigned)r;
        __builtin_nontemporal_store(gelu_fast(acc[f][r] + bv),
                                    &out[mrow * 256 + n]);
      }
    }
    __syncthreads(); // protect sm before next quarter's restage
  }
}

extern "C" void kernel_launch(void* const* d_in, const int* in_sizes, int n_in,
                              void* d_out, int out_size, void* d_ws, size_t ws_size,
                              hipStream_t stream) {
  const float* x      = (const float*)d_in[0];
  const unsigned* eid = (const unsigned*)d_in[1];
  const float* W      = (const float*)d_in[2];
  const float* bia    = (const float*)d_in[3];
  float* out          = (float*)d_out;
  unsigned* ws        = (unsigned*)d_ws;

  const unsigned short* Wt = (const unsigned short*)(ws + WT_OFF);

  // zero cnt[16384] + ovf_cnt (+pad)
  hipMemsetAsync(ws + CNT_OFF, 0, 16448 * sizeof(unsigned), stream);
  hipLaunchKernelGGL(k_prep, dim3(17536), dim3(256), 0, stream, x, eid, W, ws);
  hipLaunchKernelGGL(k_ag,   dim3(2048),  dim3(256), 0, stream,
                     (const uint4*)(ws + XBF_OFF), ws, Wt, bia, out);
}

// Round 11
// 298.592 us; speedup vs baseline: 1.1597x; 1.1597x over previous
//
#include <hip/hip_runtime.h>
#include <hip/hip_bf16.h>

// Problem constants (all powers of two -> index math is shifts/masks)
#define B_   8
#define N_   16384
#define C_   128
#define OUT_ 256
#define E_   262144

// ws word layout (uint32 offsets). ws_size ~537 MB, we use ~73.5 MB.
//   [0,        16384)    : cnt[row]; memset 0 -> per-row edge count (may exceed 64)
//   [16384,    16448)    : ovf_cnt (word 16384) + pad; memset covers it
//   [16448,    540736)   : overflow (row,col) pairs - correctness path only
//   [540736,   1589312)  : tab: fixed-capacity col table, 64 slots/row (16384*64)
//   [1589312,  1605696)  : Wt bf16 [n][k] transposed weights (256x128)
//   [1605696,  9994304)  : x_bf bf16 copy of x (B*N*C shorts)
//   [9994304,  18382912) : aggr bf16 (max_j x_j - x_i), row-major (b,row,c)
#define CNT_OFF  0u
#define OVFC_OFF 16384u
#define OVF_OFF  16448u
#define TAB_OFF  540736u
#define WT_OFF   1589312u
#define XBF_OFF  1605696u
#define AGGR_OFF 9994304u

typedef __attribute__((ext_vector_type(8))) short bf16x8; // 8 bf16 = 4 VGPRs
typedef __attribute__((ext_vector_type(4))) float f32x4;

__device__ __forceinline__ unsigned short f2bf(float f) { // RNE, no NaN inputs
  unsigned u = __float_as_uint(f);
  u += 0x7FFFu + ((u >> 16) & 1u);
  return (unsigned short)(u >> 16);
}
// Fast GELU (R10 accuracy-verified on this problem: absmax stayed 0.0078125).
// tanh-form via hw exp2 + v_rcp (~12 ops) replaces libm erff (~40-op branchy).
__device__ __forceinline__ float gelu_fast(float x) {
  float x2 = x * x;
  float inner = fmaf(0.0356774081f, x2, 0.7978845608f); // sqrt(2/pi)*(1+0.044715x^2)
  float y2l = fminf(x * inner * 2.8853900818f, 126.0f); // 2y*log2(e), ovf-clamped
  float z = exp2f(y2l);                                 // e^{2y}, hw v_exp_f32
  float t = (z - 1.0f) * __builtin_amdgcn_rcpf(z + 1.0f); // tanh(y)
  float h = 0.5f * x;
  return fmaf(h, t, h); // 0.5x(1+tanh(y))
}
__device__ __forceinline__ unsigned umin_(unsigned a, unsigned b) {
  return a < b ? a : b;
}

// ------------- kernel 1: fused x->bf16 | direct edge-table build | Wt prep ------
// Fixed-capacity table (64 slots/row) built in ONE edge pass with atomic cursors
// (aggr needs the col SET, not order). Overflow rows (P ~ 1e-14 at Poisson(16))
// spill (row,col) pairs to a global list that aggr replays -> correct for ANY
// input. Per-block dtype detect: odd u32 words are int64-highs (==0) or int32
// index values (nonzero w.h.p.); 256 samples/block -> P(wrong) = 16384^-256 ~ 0.
__global__ __launch_bounds__(256) void k_prep(const float* __restrict__ x,
                                              const unsigned* __restrict__ eidx,
                                              const float* __restrict__ W,
                                              unsigned* __restrict__ ws) {
  const unsigned bid = blockIdx.x, tid = threadIdx.x;
  if (bid < 16384u) { // ---- x fp32 -> bf16 packed (4,194,304 float4 slots)
    unsigned i = bid * 256u + tid;
    float4 v = ((const float4*)x)[i];
    uint2 o;
    o.x = (unsigned)f2bf(v.x) | ((unsigned)f2bf(v.y) << 16);
    o.y = (unsigned)f2bf(v.z) | ((unsigned)f2bf(v.w) << 16);
    ((uint2*)(ws + XBF_OFF))[i] = o;
  } else if (bid < 17408u) { // ---- edge-table build, one edge per thread
    __shared__ int flag32;
    if (tid == 0) flag32 = 0;
    __syncthreads();
    unsigned e = (bid - 16384u) * 256u + tid; // 0..262143
    if (eidx[2u * e + 1u] != 0u) flag32 = 1;  // benign race
    __syncthreads();
    int row, col;
    if (flag32) {
      row = (int)eidx[e];
      col = (int)eidx[e + E_];
    } else {
      const long long* p = (const long long*)eidx;
      row = (int)p[e];
      col = (int)p[e + E_];
    }
    unsigned pos = atomicAdd(ws + CNT_OFF + (unsigned)row, 1u);
    if (pos < 64u) {
      ws[TAB_OFF + ((unsigned)row << 6) + pos] = (unsigned)col;
    } else { // correctness-only spill
      unsigned o = atomicAdd(ws + OVFC_OFF, 1u);
      ws[OVF_OFF + 2u * o]      = (unsigned)row;
      ws[OVF_OFF + 2u * o + 1u] = (unsigned)col;
    }
  } else { // ---- W fp32 -> bf16 transposed (128 blocks)
    unsigned t = (bid - 17408u) * 256u + tid; // 0..32767
    unsigned n = t >> 7, k = t & 127u;
    ((unsigned short*)(ws + WT_OFF))[n * 128u + k] = f2bf(W[k * 256u + n]);
  }
}

// ------------ kernel 2: full-row table gather-max, clamped-parallel (bf16) ------
// R3's best-measured aggr (session-best total 284.5 came with this): one wave
// per (batch,row); 64 lanes = 4 edge-groups x 16 lanes; each lane loads uint4
// (8 channels) -> one wave-load gathers 4 edges x full 128-ch row (1 KB).
// Max is IDEMPOTENT -> round the edge count up and CLAMP the slot index
// (min(4i+g, d64-1)): every row is a branch-free all-parallel gather
// (deg<=16: 4 loads, deg<=32: 8 loads, rare deg>32: clamped 16-chunk loop).
// R5-R10 fused redesigns were all slower (barrier phases + 40% occ + sticky
// spill); reverted. R11 grafts: nt TAB/OVF loads (R7-proven FETCH hygiene).
// EXEC discipline (R1 bug): every __shfl under wave-uniform control flow.
// Max trick: fmax on raw u32 (hi channel; garbage low mantissa can't flip a
// bf16-level compare) and on u<<16 (lo channel, exact). batch = blockIdx&7.
__global__ __launch_bounds__(256) void k_aggr(const uint4* __restrict__ xbf4,
                                              const unsigned* __restrict__ ws,
                                              uint4* __restrict__ aggr4) {
  const unsigned bi = blockIdx.x;            // 32768 = 4096 rowgroups x 8 batches
  const unsigned b  = bi & 7u;
  const unsigned rg = bi >> 3;               // 0..4095
  const unsigned row = (rg << 2) | (threadIdx.x >> 6); // wave <-> row
  const unsigned lane = threadIdx.x & 63u;
  const unsigned g  = lane >> 4;             // edge subgroup 0..3
  const unsigned ln = lane & 15u;            // uint4 slot within the row
  const uint4* xb = xbf4 + ((size_t)b << 18); // rows stride 16 uint4

  const unsigned deg = ws[CNT_OFF + row];    // wave-uniform (row is per-wave)
  const bool has = (deg != 0u);
  const unsigned d64 = deg < 64u ? deg : 64u;

  // issue all prologue loads up front: col slots (nt: read-once stream shared
  // by all XCDs -> don't evict x_bf), own row (epilogue operand)
  const unsigned cpre =
      __builtin_nontemporal_load(ws + TAB_OFF + (row << 6) + lane);
  const uint4 xw = xb[((size_t)row << 4) + ln];

  float mlo[4], mhi[4];
#pragma unroll
  for (int r = 0; r < 4; ++r) { mlo[r] = -INFINITY; mhi[r] = -INFINITY; }

#define MAX1(a, r)                                                          \
  mhi[r] = fmaxf(mhi[r], __uint_as_float(a));                               \
  mlo[r] = fmaxf(mlo[r], __uint_as_float((a) << 16));
#define MAX2(a, c, r)                                                       \
  mhi[r] = fmaxf(mhi[r], fmaxf(__uint_as_float(a), __uint_as_float(c)));    \
  mlo[r] = fmaxf(mlo[r],                                                    \
      fmaxf(__uint_as_float((a) << 16), __uint_as_float((c) << 16)));

  if (has) { // wave-uniform
    const unsigned dm1 = d64 - 1u;
    if (d64 <= 16u) { // ---- 4 clamped loads, fully parallel (P = .57)
      unsigned c0 = (unsigned)__shfl((int)cpre, (int)umin_(g,       dm1));
      unsigned c1 = (unsigned)__shfl((int)cpre, (int)umin_(4u + g,  dm1));
      unsigned c2 = (unsigned)__shfl((int)cpre, (int)umin_(8u + g,  dm1));
      unsigned c3 = (unsigned)__shfl((int)cpre, (int)umin_(12u + g, dm1));
      uint4 u0 = xb[((size_t)c0 << 4) + ln];
      uint4 u1 = xb[((size_t)c1 << 4) + ln];
      uint4 u2 = xb[((size_t)c2 << 4) + ln];
      uint4 u3 = xb[((size_t)c3 << 4) + ln];
      MAX2(u0.x, u1.x, 0) MAX2(u0.y, u1.y, 1)
      MAX2(u0.z, u1.z, 2) MAX2(u0.w, u1.w, 3)
      MAX2(u2.x, u3.x, 0) MAX2(u2.y, u3.y, 1)
      MAX2(u2.z, u3.z, 2) MAX2(u2.w, u3.w, 3)
    } else if (d64 <= 32u) { // ---- 8 clamped loads, fully parallel (P = .9999)
      unsigned c[8];
#pragma unroll
      for (int i = 0; i < 8; ++i)
        c[i] = (unsigned)__shfl((int)cpre, (int)umin_(4u * i + g, dm1));
      uint4 u[8];
#pragma unroll
      for (int i = 0; i < 8; ++i) u[i] = xb[((size_t)c[i] << 4) + ln];
#pragma unroll
      for (int i = 0; i < 8; i += 2) {
        MAX2(u[i].x, u[i + 1].x, 0) MAX2(u[i].y, u[i + 1].y, 1)
        MAX2(u[i].z, u[i + 1].z, 2) MAX2(u[i].w, u[i + 1].w, 3)
      }
    } else { // ---- rare: clamped 16-chunk loop, wave-uniform trip count
      for (unsigned t = 0u; t < d64; t += 16u) {
        unsigned c0 = (unsigned)__shfl((int)cpre, (int)umin_(t + g,       dm1));
        unsigned c1 = (unsigned)__shfl((int)cpre, (int)umin_(t + 4u + g,  dm1));
        unsigned c2 = (unsigned)__shfl((int)cpre, (int)umin_(t + 8u + g,  dm1));
        unsigned c3 = (unsigned)__shfl((int)cpre, (int)umin_(t + 12u + g, dm1));
        uint4 u0 = xb[((size_t)c0 << 4) + ln];
        uint4 u1 = xb[((size_t)c1 << 4) + ln];
        uint4 u2 = xb[((size_t)c2 << 4) + ln];
        uint4 u3 = xb[((size_t)c3 << 4) + ln];
        MAX2(u0.x, u1.x, 0) MAX2(u0.y, u1.y, 1)
        MAX2(u0.z, u1.z, 2) MAX2(u0.w, u1.w, 3)
        MAX2(u2.x, u3.x, 0) MAX2(u2.y, u3.y, 1)
        MAX2(u2.z, u3.z, 2) MAX2(u2.w, u3.w, 3)
      }
    }
  }
  if (deg > 64u) { // overflow replay: correctness-only, shuffle-free
    unsigned no = ws[OVFC_OFF];
    for (unsigned i = 0u; i < no; i += 4u) {
      unsigned k = i + g;
      if (k < no && __builtin_nontemporal_load(ws + OVF_OFF + 2u * k) == row) {
        unsigned c = ws[OVF_OFF + 2u * k + 1u];
        uint4 u = xb[((size_t)c << 4) + ln];
        MAX1(u.x, 0) MAX1(u.y, 1) MAX1(u.z, 2) MAX1(u.w, 3)
      }
    }
  }
#undef MAX1
#undef MAX2

  // reduce the 4 edge-groups (lane bits 4,5); full EXEC here (reconverged)
#pragma unroll
  for (int r = 0; r < 4; ++r) {
    mlo[r] = fmaxf(mlo[r], __shfl_xor(mlo[r], 16, 64));
    mhi[r] = fmaxf(mhi[r], __shfl_xor(mhi[r], 16, 64));
  }
#pragma unroll
  for (int r = 0; r < 4; ++r) {
    mlo[r] = fmaxf(mlo[r], __shfl_xor(mlo[r], 32, 64));
    mhi[r] = fmaxf(mhi[r], __shfl_xor(mhi[r], 32, 64));
  }

  if (g == 0u) {
    unsigned xv[4] = {xw.x, xw.y, xw.z, xw.w};
    unsigned ox[4];
#pragma unroll
    for (int r = 0; r < 4; ++r) {
      float vlo = has ? mlo[r] : 0.0f;
      float vhi = has ? __uint_as_float(__float_as_uint(mhi[r]) & 0xFFFF0000u)
                      : 0.0f;
      unsigned lo = f2bf(vlo - __uint_as_float(xv[r] << 16));
      unsigned hi = f2bf(vhi - __uint_as_float(xv[r] & 0xFFFF0000u));
      ox[r] = lo | (hi << 16);
    }
    uint4 o = {ox[0], ox[1], ox[2], ox[3]};
    // NOT nontemporal: k_gemm reads aggr right after -> keep L2/L3-warm.
    aggr4[(((size_t)b << 14) + row) * 16u + ln] = o;
  }
}

// ---------------- kernel 3: aggr(bf16) @ Wt(bf16) + b, fast GELU ----------------
// R3's best-measured gemm, verbatim, except: gelu_fast (R10-verified) and
// nontemporal out stores (write-once; keep caches for aggr/Wt).
// A-fragments read directly from global (the 4 unrolled kc loads cover full
// 64B lines per row; aggr is cache-warm from k_aggr). LDS = Wt only -> 4 blk/CU.
__global__ __launch_bounds__(256, 4) void k_gemm(const unsigned short* __restrict__ aggr,
                                                 const unsigned short* __restrict__ Wt,
                                                 const float* __restrict__ bias,
                                                 float* __restrict__ out) {
  __shared__ unsigned short Wt_sm[128 * 136]; // 34816 B; stride 136 (2-way free)
  const int tid = threadIdx.x;
  const int nbase = blockIdx.x * 128; // n-tiles adjacent in dispatch: A re-read
  const int mbase = blockIdx.y * 64;  // of the same m-tile stays cache-warm

#pragma unroll
  for (int i = 0; i < 8; ++i) {
    int slot = i * 256 + tid;
    int n = slot >> 4, k8 = slot & 15;
    uint4 u = *(const uint4*)(Wt + (size_t)(nbase + n) * 128 + k8 * 8);
    *(uint4*)&Wt_sm[n * 136 + k8 * 8] = u;
  }
  __syncthreads();

  const int lane = tid & 63;
  const int wv = tid >> 6;   // wave id: rows [wv*16, wv*16+16)
  const int ln = lane & 15;
  const int q = lane >> 4;   // quad

  // A-operand: A[m = lane&15][k = quad*8 + j] -> 16B contiguous in global
  const unsigned short* arow = aggr + (size_t)(mbase + wv * 16 + ln) * 128 + q * 8;
  bf16x8 af[4];
#pragma unroll
  for (int kc = 0; kc < 4; ++kc) af[kc] = *(const bf16x8*)(arow + kc * 32);

  f32x4 acc[8];
#pragma unroll
  for (int f = 0; f < 8; ++f) acc[f] = (f32x4){0.f, 0.f, 0.f, 0.f};

#pragma unroll
  for (int kc = 0; kc < 4; ++kc) {
#pragma unroll
    for (int f = 0; f < 8; ++f) {
      // B-operand: B[k = quad*8 + j][n = lane&15] contiguous in Wt[n][k]
      bf16x8 bf = *(const bf16x8*)&Wt_sm[(f * 16 + ln) * 136 + kc * 32 + q * 8];
      acc[f] = __builtin_amdgcn_mfma_f32_16x16x32_bf16(af[kc], bf, acc[f], 0, 0, 0);
    }
  }

  // Epilogue: C/D layout col = lane&15, row = quad*4 + reg (m89-verified)
#pragma unroll
  for (int f = 0; f < 8; ++f) {
    int n = nbase + f * 16 + ln;
    float bv = bias[n];
#pragma unroll
    for (int r = 0; r < 4; ++r) {
      int m = mbase + wv * 16 + q * 4 + r;
      __builtin_nontemporal_store(gelu_fast(acc[f][r] + bv),
                                  &out[(size_t)m * 256 + n]);
    }
  }
}

extern "C" void kernel_launch(void* const* d_in, const int* in_sizes, int n_in,
                              void* d_out, int out_size, void* d_ws, size_t ws_size,
                              hipStream_t stream) {
  const float* x      = (const float*)d_in[0];
  const unsigned* eid = (const unsigned*)d_in[1];
  const float* W      = (const float*)d_in[2];
  const float* bia    = (const float*)d_in[3];
  float* out          = (float*)d_out;
  unsigned* ws        = (unsigned*)d_ws;

  unsigned short* Wt   = (unsigned short*)(ws + WT_OFF);
  unsigned short* aggr = (unsigned short*)(ws + AGGR_OFF);

  // zero cnt[16384] + ovf_cnt (+pad)
  hipMemsetAsync(ws + CNT_OFF, 0, 16448 * sizeof(unsigned), stream);
  hipLaunchKernelGGL(k_prep, dim3(17536),   dim3(256), 0, stream, x, eid, W, ws);
  hipLaunchKernelGGL(k_aggr, dim3(32768),   dim3(256), 0, stream,
                     (const uint4*)(ws + XBF_OFF), ws, (uint4*)(ws + AGGR_OFF));
  hipLaunchKernelGGL(k_gemm, dim3(2, 2048), dim3(256), 0, stream,
                     aggr, Wt, bia, out);
}

// Round 12
// 271.381 us; speedup vs baseline: 1.2760x; 1.1003x over previous
//
#include <hip/hip_runtime.h>
#include <hip/hip_bf16.h>

// Problem constants (all powers of two -> index math is shifts/masks)
#define B_   8
#define N_   16384
#define C_   128
#define OUT_ 256
#define E_   262144

// ws word layout (uint32 offsets). ws_size ~537 MB, we use ~73.5 MB.
//   [0,        16384)    : cnt[row]; memset 0 -> per-row edge count (may exceed 64)
//   [16384,    16448)    : ovf_cnt (word 16384) + pad; memset covers it
//   [16448,    540736)   : overflow (row,col) pairs - correctness path only
//   [540736,   1589312)  : tab: fixed-capacity col table, 64 slots/row (16384*64)
//   [1589312,  1605696)  : Wt bf16 [n][k] transposed weights (256x128)
//   [1605696,  9994304)  : x_bf bf16 copy of x, ORDER-MAP TRANSFORMED (see fwdmap)
//   [9994304,  18382912) : aggr bf16 (max_j x_j - x_i), row-major (b,row,c), PLAIN
#define CNT_OFF  0u
#define OVFC_OFF 16384u
#define OVF_OFF  16448u
#define TAB_OFF  540736u
#define WT_OFF   1589312u
#define XBF_OFF  1605696u
#define AGGR_OFF 9994304u

typedef __attribute__((ext_vector_type(8))) short bf16x8; // 8 bf16 = 4 VGPRs
typedef __attribute__((ext_vector_type(4))) float f32x4;

__device__ __forceinline__ unsigned short f2bf(float f) { // RNE, no NaN inputs
  unsigned u = __float_as_uint(f);
  u += 0x7FFFu + ((u >> 16) & 1u);
  return (unsigned short)(u >> 16);
}
// Fast GELU (R10 accuracy-verified on this problem: absmax stayed 0.0078125).
__device__ __forceinline__ float gelu_fast(float x) {
  float x2 = x * x;
  float inner = fmaf(0.0356774081f, x2, 0.7978845608f); // sqrt(2/pi)*(1+0.044715x^2)
  float y2l = fminf(x * inner * 2.8853900818f, 126.0f); // 2y*log2(e), ovf-clamped
  float z = exp2f(y2l);                                 // e^{2y}, hw v_exp_f32
  float t = (z - 1.0f) * __builtin_amdgcn_rcpf(z + 1.0f); // tanh(y)
  float h = 0.5f * x;
  return fmaf(h, t, h); // 0.5x(1+tanh(y))
}
__device__ __forceinline__ unsigned umin_(unsigned a, unsigned b) {
  return a < b ? a : b;
}
// R12: order-preserving bf16<->u16 map (per 16-bit half of a packed u32).
// m(h) = h ^ (sign ? 0xFFFF : 0x8000): monotone bijection -> bf16 max becomes
// UNSIGNED u16 max -> one v_pk_max_u16 per 2 channels (replaces 4 fmax + 2 shl).
// No NaN/Inf in x by construction (f2bf of finite normals).
__device__ __forceinline__ unsigned fwdmap(unsigned u) {
  unsigned s = u & 0x80008000u;
  return u ^ (0x80008000u | ((s >> 15) * 0x7FFFu));
}
__device__ __forceinline__ unsigned invmap(unsigned u) {
  unsigned nm = (~u) & 0x80008000u;
  return u ^ (0x80008000u | ((nm >> 15) * 0x7FFFu));
}
__device__ __forceinline__ unsigned pkmax(unsigned a, unsigned b) {
  unsigned d;
  asm("v_pk_max_u16 %0, %1, %2" : "=v"(d) : "v"(a), "v"(b));
  return d;
}

// ------------- kernel 1: fused x->bf16(transformed) | edge-table | Wt prep ------
// Fixed-capacity table (64 slots/row) built in ONE edge pass with atomic cursors
// (aggr needs the col SET, not order). Overflow rows (P ~ 1e-14 at Poisson(16))
// spill (row,col) pairs to a global list that aggr replays -> correct for ANY
// input. x_bf is stored ORDER-MAPPED (fwdmap) so the gather uses v_pk_max_u16.
// Per-block dtype detect: odd u32 words are int64-highs (==0) or int32 index
// values (nonzero w.h.p.); 256 samples/block -> P(wrong) = 16384^-256 ~ 0.
__global__ __launch_bounds__(256) void k_prep(const float* __restrict__ x,
                                              const unsigned* __restrict__ eidx,
                                              const float* __restrict__ W,
                                              unsigned* __restrict__ ws) {
  const unsigned bid = blockIdx.x, tid = threadIdx.x;
  if (bid < 16384u) { // ---- x fp32 -> bf16 packed + fwdmap (4,194,304 slots)
    unsigned i = bid * 256u + tid;
    float4 v = ((const float4*)x)[i];
    uint2 o;
    o.x = fwdmap((unsigned)f2bf(v.x) | ((unsigned)f2bf(v.y) << 16));
    o.y = fwdmap((unsigned)f2bf(v.z) | ((unsigned)f2bf(v.w) << 16));
    ((uint2*)(ws + XBF_OFF))[i] = o;
  } else if (bid < 17408u) { // ---- edge-table build, one edge per thread
    __shared__ int flag32;
    if (tid == 0) flag32 = 0;
    __syncthreads();
    unsigned e = (bid - 16384u) * 256u + tid; // 0..262143
    if (eidx[2u * e + 1u] != 0u) flag32 = 1;  // benign race
    __syncthreads();
    int row, col;
    if (flag32) {
      row = (int)eidx[e];
      col = (int)eidx[e + E_];
    } else {
      const long long* p = (const long long*)eidx;
      row = (int)p[e];
      col = (int)p[e + E_];
    }
    unsigned pos = atomicAdd(ws + CNT_OFF + (unsigned)row, 1u);
    if (pos < 64u) {
      ws[TAB_OFF + ((unsigned)row << 6) + pos] = (unsigned)col;
    } else { // correctness-only spill
      unsigned o = atomicAdd(ws + OVFC_OFF, 1u);
      ws[OVF_OFF + 2u * o]      = (unsigned)row;
      ws[OVF_OFF + 2u * o + 1u] = (unsigned)col;
    }
  } else { // ---- W fp32 -> bf16 transposed (128 blocks)
    unsigned t = (bid - 17408u) * 256u + tid; // 0..32767
    unsigned n = t >> 7, k = t & 127u;
    ((unsigned short*)(ws + WT_OFF))[n * 128u + k] = f2bf(W[k * 256u + n]);
  }
}

// ------------ kernel 2: full-row table gather-max, packed-u16 max (bf16) --------
// R11 counters: VALUBusy 75%, HBM 15%, 0 spill, FETCH fully explained (x slice
// per XCD + tab per XCD) -> VALU-ISSUE-BOUND. R12 cuts the dominant VALU term:
// x_bf is order-mapped, so per-u32 max = ONE v_pk_max_u16 (was 4 fmax + 2 shl);
// reduce = 8 shuffle + 8 pk_max (was 16+16); accumulator state halves.
// Structure unchanged (R3/R4-proven best): one wave per (batch,row); 64 lanes =
// 4 edge-groups x 16 lanes; lane loads uint4 (8 ch) -> wave-load = 4 edges x
// full 128-ch row. Max is IDEMPOTENT -> clamp slot index (min(4i+g, d64-1)):
// branch-free all-parallel gather (deg<=16: 4 loads, <=32: 8, rare: loop).
// EXEC discipline (R1 bug): every __shfl under wave-uniform control flow.
// batch = blockIdx&7 <-> XCD under round-robin: per-XCD x-slice is L2-sized.
__global__ __launch_bounds__(256) void k_aggr(const uint4* __restrict__ xbf4,
                                              const unsigned* __restrict__ ws,
                                              uint4* __restrict__ aggr4) {
  const unsigned bi = blockIdx.x;            // 32768 = 4096 rowgroups x 8 batches
  const unsigned b  = bi & 7u;
  const unsigned rg = bi >> 3;               // 0..4095
  const unsigned row = (rg << 2) | (threadIdx.x >> 6); // wave <-> row
  const unsigned lane = threadIdx.x & 63u;
  const unsigned g  = lane >> 4;             // edge subgroup 0..3
  const unsigned ln = lane & 15u;            // uint4 slot within the row
  const uint4* xb = xbf4 + ((size_t)b << 18); // rows stride 16 uint4

  const unsigned deg = ws[CNT_OFF + row];    // wave-uniform (row is per-wave)
  const bool has = (deg != 0u);
  const unsigned d64 = deg < 64u ? deg : 64u;

  // issue prologue loads up front: col slots (cached: every XCD refills tab
  // once regardless - R11 FETCH arithmetic), own row (epilogue operand)
  const unsigned cpre = ws[TAB_OFF + (row << 6) + lane];
  const uint4 xw = xb[((size_t)row << 4) + ln]; // transformed; inv in epilogue

  unsigned mx[4] = {0u, 0u, 0u, 0u}; // transformed-space max (0 = below all reals)

#define MAXP(U)                                                             \
  mx[0] = pkmax(mx[0], (U).x); mx[1] = pkmax(mx[1], (U).y);                 \
  mx[2] = pkmax(mx[2], (U).z); mx[3] = pkmax(mx[3], (U).w);
#define MAXP2(U, V)                                                         \
  mx[0] = pkmax(mx[0], pkmax((U).x, (V).x));                                \
  mx[1] = pkmax(mx[1], pkmax((U).y, (V).y));                                \
  mx[2] = pkmax(mx[2], pkmax((U).z, (V).z));                                \
  mx[3] = pkmax(mx[3], pkmax((U).w, (V).w));

  if (has) { // wave-uniform
    const unsigned dm1 = d64 - 1u;
    if (d64 <= 16u) { // ---- 4 clamped loads, fully parallel (P = .57)
      unsigned c0 = (unsigned)__shfl((int)cpre, (int)umin_(g,       dm1));
      unsigned c1 = (unsigned)__shfl((int)cpre, (int)umin_(4u + g,  dm1));
      unsigned c2 = (unsigned)__shfl((int)cpre, (int)umin_(8u + g,  dm1));
      unsigned c3 = (unsigned)__shfl((int)cpre, (int)umin_(12u + g, dm1));
      uint4 u0 = xb[((size_t)c0 << 4) + ln];
      uint4 u1 = xb[((size_t)c1 << 4) + ln];
      uint4 u2 = xb[((size_t)c2 << 4) + ln];
      uint4 u3 = xb[((size_t)c3 << 4) + ln];
      MAXP2(u0, u1) MAXP2(u2, u3)
    } else if (d64 <= 32u) { // ---- 8 clamped loads, fully parallel (P = .9999)
      unsigned c[8];
#pragma unroll
      for (int i = 0; i < 8; ++i)
        c[i] = (unsigned)__shfl((int)cpre, (int)umin_(4u * i + g, dm1));
      uint4 u[8];
#pragma unroll
      for (int i = 0; i < 8; ++i) u[i] = xb[((size_t)c[i] << 4) + ln];
#pragma unroll
      for (int i = 0; i < 8; i += 2) { MAXP2(u[i], u[i + 1]) }
    } else { // ---- rare: clamped 16-chunk loop, wave-uniform trip count
      for (unsigned t = 0u; t < d64; t += 16u) {
        unsigned c0 = (unsigned)__shfl((int)cpre, (int)umin_(t + g,       dm1));
        unsigned c1 = (unsigned)__shfl((int)cpre, (int)umin_(t + 4u + g,  dm1));
        unsigned c2 = (unsigned)__shfl((int)cpre, (int)umin_(t + 8u + g,  dm1));
        unsigned c3 = (unsigned)__shfl((int)cpre, (int)umin_(t + 12u + g, dm1));
        uint4 u0 = xb[((size_t)c0 << 4) + ln];
        uint4 u1 = xb[((size_t)c1 << 4) + ln];
        uint4 u2 = xb[((size_t)c2 << 4) + ln];
        uint4 u3 = xb[((size_t)c3 << 4) + ln];
        MAXP2(u0, u1) MAXP2(u2, u3)
      }
    }
  }
  if (deg > 64u) { // overflow replay: correctness-only, shuffle-free
    unsigned no = ws[OVFC_OFF];
    for (unsigned i = 0u; i < no; i += 4u) {
      unsigned k = i + g;
      if (k < no && ws[OVF_OFF + 2u * k] == row) {
        unsigned c = ws[OVF_OFF + 2u * k + 1u];
        uint4 u = xb[((size_t)c << 4) + ln];
        MAXP(u)
      }
    }
  }
#undef MAXP
#undef MAXP2

  // reduce the 4 edge-groups (lane bits 4,5); full EXEC here (reconverged)
#pragma unroll
  for (int r = 0; r < 4; ++r)
    mx[r] = pkmax(mx[r], (unsigned)__shfl_xor((int)mx[r], 16, 64));
#pragma unroll
  for (int r = 0; r < 4; ++r)
    mx[r] = pkmax(mx[r], (unsigned)__shfl_xor((int)mx[r], 32, 64));

  if (g == 0u) {
    unsigned xv[4] = {xw.x, xw.y, xw.z, xw.w};
    unsigned ox[4];
#pragma unroll
    for (int r = 0; r < 4; ++r) {
      // back to real bf16 bit-space; empty row -> max := +0.0 pair
      unsigned m = has ? invmap(mx[r]) : 0u;
      unsigned xr = invmap(xv[r]);
      float mlo = __uint_as_float(m << 16);
      float mhi = __uint_as_float(m & 0xFFFF0000u);
      float xlo = __uint_as_float(xr << 16);
      float xhi = __uint_as_float(xr & 0xFFFF0000u);
      ox[r] = (unsigned)f2bf(mlo - xlo) | ((unsigned)f2bf(mhi - xhi) << 16);
    }
    uint4 o = {ox[0], ox[1], ox[2], ox[3]};
    // NOT nontemporal: k_gemm reads aggr right after -> keep caches warm.
    aggr4[(((size_t)b << 14) + row) * 16u + ln] = o;
  }
}

// ---------------- kernel 3: aggr(bf16) @ Wt(bf16) + b, fast GELU ----------------
// R3-structure gemm + gelu_fast (R10-verified) + nontemporal out stores.
// A-fragments read directly from global (aggr is cache-warm from k_aggr).
// LDS = Wt only -> 4 blocks/CU.
__global__ __launch_bounds__(256, 4) void k_gemm(const unsigned short* __restrict__ aggr,
                                                 const unsigned short* __restrict__ Wt,
                                                 const float* __restrict__ bias,
                                                 float* __restrict__ out) {
  __shared__ unsigned short Wt_sm[128 * 136]; // 34816 B; stride 136 (2-way free)
  const int tid = threadIdx.x;
  const int nbase = blockIdx.x * 128; // n-tiles adjacent in dispatch: A re-read
  const int mbase = blockIdx.y * 64;  // of the same m-tile stays cache-warm

#pragma unroll
  for (int i = 0; i < 8; ++i) {
    int slot = i * 256 + tid;
    int n = slot >> 4, k8 = slot & 15;
    uint4 u = *(const uint4*)(Wt + (size_t)(nbase + n) * 128 + k8 * 8);
    *(uint4*)&Wt_sm[n * 136 + k8 * 8] = u;
  }
  __syncthreads();

  const int lane = tid & 63;
  const int wv = tid >> 6;   // wave id: rows [wv*16, wv*16+16)
  const int ln = lane & 15;
  const int q = lane >> 4;   // quad

  // A-operand: A[m = lane&15][k = quad*8 + j] -> 16B contiguous in global
  const unsigned short* arow = aggr + (size_t)(mbase + wv * 16 + ln) * 128 + q * 8;
  bf16x8 af[4];
#pragma unroll
  for (int kc = 0; kc < 4; ++kc) af[kc] = *(const bf16x8*)(arow + kc * 32);

  f32x4 acc[8];
#pragma unroll
  for (int f = 0; f < 8; ++f) acc[f] = (f32x4){0.f, 0.f, 0.f, 0.f};

#pragma unroll
  for (int kc = 0; kc < 4; ++kc) {
#pragma unroll
    for (int f = 0; f < 8; ++f) {
      // B-operand: B[k = quad*8 + j][n = lane&15] contiguous in Wt[n][k]
      bf16x8 bf = *(const bf16x8*)&Wt_sm[(f * 16 + ln) * 136 + kc * 32 + q * 8];
      acc[f] = __builtin_amdgcn_mfma_f32_16x16x32_bf16(af[kc], bf, acc[f], 0, 0, 0);
    }
  }

  // Epilogue: C/D layout col = lane&15, row = quad*4 + reg (m89-verified)
#pragma unroll
  for (int f = 0; f < 8; ++f) {
    int n = nbase + f * 16 + ln;
    float bv = bias[n];
#pragma unroll
    for (int r = 0; r < 4; ++r) {
      int m = mbase + wv * 16 + q * 4 + r;
      __builtin_nontemporal_store(gelu_fast(acc[f][r] + bv),
                                  &out[(size_t)m * 256 + n]);
    }
  }
}

extern "C" void kernel_launch(void* const* d_in, const int* in_sizes, int n_in,
                              void* d_out, int out_size, void* d_ws, size_t ws_size,
                              hipStream_t stream) {
  const float* x      = (const float*)d_in[0];
  const unsigned* eid = (const unsigned*)d_in[1];
  const float* W      = (const float*)d_in[2];
  const float* bia    = (const float*)d_in[3];
  float* out          = (float*)d_out;
  unsigned* ws        = (unsigned*)d_ws;

  unsigned short* Wt   = (unsigned short*)(ws + WT_OFF);
  unsigned short* aggr = (unsigned short*)(ws + AGGR_OFF);

  // zero cnt[16384] + ovf_cnt (+pad)
  hipMemsetAsync(ws + CNT_OFF, 0, 16448 * sizeof(unsigned), stream);
  hipLaunchKernelGGL(k_prep, dim3(17536),   dim3(256), 0, stream, x, eid, W, ws);
  hipLaunchKernelGGL(k_aggr, dim3(32768),   dim3(256), 0, stream,
                     (const uint4*)(ws + XBF_OFF), ws, (uint4*)(ws + AGGR_OFF));
  hipLaunchKernelGGL(k_gemm, dim3(2, 2048), dim3(256), 0, stream,
                     aggr, Wt, bia, out);
}

// Round 13
// 266.099 us; speedup vs baseline: 1.3013x; 1.0198x over previous
//
#include <hip/hip_runtime.h>
#include <hip/hip_bf16.h>

// Problem constants (all powers of two -> index math is shifts/masks)
#define B_   8
#define N_   16384
#define C_   128
#define OUT_ 256
#define E_   262144

// ws word layout (uint32 offsets). ws_size ~537 MB, we use ~73.5 MB.
//   [0,        16384)    : cnt[row]; memset 0 -> per-row edge count (may exceed 64)
//   [16384,    16448)    : ovf_cnt (word 16384) + pad; memset covers it
//   [16448,    540736)   : overflow (row,col) pairs - correctness path only
//   [540736,   1589312)  : tab: fixed-capacity col table, 64 slots/row (16384*64)
//   [1589312,  1605696)  : Wt bf16 [n][k] transposed weights (256x128)
//   [1605696,  9994304)  : x_bf bf16 copy of x, ORDER-MAP TRANSFORMED (see fwdmap)
//   [9994304,  18382912) : aggr bf16 (max_j x_j - x_i), row-major (b,row,c), PLAIN
#define CNT_OFF  0u
#define OVFC_OFF 16384u
#define OVF_OFF  16448u
#define TAB_OFF  540736u
#define WT_OFF   1589312u
#define XBF_OFF  1605696u
#define AGGR_OFF 9994304u

typedef __attribute__((ext_vector_type(8))) short bf16x8; // 8 bf16 = 4 VGPRs
typedef __attribute__((ext_vector_type(4))) float f32x4;

__device__ __forceinline__ unsigned short f2bf(float f) { // RNE, no NaN inputs
  unsigned u = __float_as_uint(f);
  u += 0x7FFFu + ((u >> 16) & 1u);
  return (unsigned short)(u >> 16);
}
// Fast GELU (R10 accuracy-verified on this problem: absmax stayed 0.0078125).
__device__ __forceinline__ float gelu_fast(float x) {
  float x2 = x * x;
  float inner = fmaf(0.0356774081f, x2, 0.7978845608f); // sqrt(2/pi)*(1+0.044715x^2)
  float y2l = fminf(x * inner * 2.8853900818f, 126.0f); // 2y*log2(e), ovf-clamped
  float z = exp2f(y2l);                                 // e^{2y}, hw v_exp_f32
  float t = (z - 1.0f) * __builtin_amdgcn_rcpf(z + 1.0f); // tanh(y)
  float h = 0.5f * x;
  return fmaf(h, t, h); // 0.5x(1+tanh(y))
}
__device__ __forceinline__ unsigned umin_(unsigned a, unsigned b) {
  return a < b ? a : b;
}
// Order-preserving bf16<->u16 map (per 16-bit half of a packed u32).
// m(h) = h ^ (sign ? 0xFFFF : 0x8000): monotone bijection -> bf16 max becomes
// UNSIGNED u16 max -> one v_pk_max_u16 per 2 channels. No NaN/Inf in x.
__device__ __forceinline__ unsigned fwdmap(unsigned u) {
  unsigned s = u & 0x80008000u;
  return u ^ (0x80008000u | ((s >> 15) * 0x7FFFu));
}
__device__ __forceinline__ unsigned invmap(unsigned u) {
  unsigned nm = (~u) & 0x80008000u;
  return u ^ (0x80008000u | ((nm >> 15) * 0x7FFFu));
}
__device__ __forceinline__ unsigned pkmax(unsigned a, unsigned b) {
  unsigned d;
  asm("v_pk_max_u16 %0, %1, %2" : "=v"(d) : "v"(a), "v"(b));
  return d;
}

// ------------- kernel 1: fused x->bf16(transformed) | edge-table | Wt prep ------
// Fixed-capacity table (64 slots/row) built in ONE edge pass with atomic cursors
// (aggr needs the col SET, not order). Overflow rows (P ~ 1e-14 at Poisson(16))
// spill (row,col) pairs to a global list that aggr replays -> correct for ANY
// input. x_bf is stored ORDER-MAPPED (fwdmap) so the gather uses v_pk_max_u16.
// At HBM roofline (R12 ledger: reads x 134 MB + writes 33.5 -> ~26 us floor).
__global__ __launch_bounds__(256) void k_prep(const float* __restrict__ x,
                                              const unsigned* __restrict__ eidx,
                                              const float* __restrict__ W,
                                              unsigned* __restrict__ ws) {
  const unsigned bid = blockIdx.x, tid = threadIdx.x;
  if (bid < 16384u) { // ---- x fp32 -> bf16 packed + fwdmap (4,194,304 slots)
    unsigned i = bid * 256u + tid;
    float4 v = ((const float4*)x)[i];
    uint2 o;
    o.x = fwdmap((unsigned)f2bf(v.x) | ((unsigned)f2bf(v.y) << 16));
    o.y = fwdmap((unsigned)f2bf(v.z) | ((unsigned)f2bf(v.w) << 16));
    ((uint2*)(ws + XBF_OFF))[i] = o;
  } else if (bid < 17408u) { // ---- edge-table build, one edge per thread
    __shared__ int flag32;
    if (tid == 0) flag32 = 0;
    __syncthreads();
    unsigned e = (bid - 16384u) * 256u + tid; // 0..262143
    if (eidx[2u * e + 1u] != 0u) flag32 = 1;  // benign race
    __syncthreads();
    int row, col;
    if (flag32) {
      row = (int)eidx[e];
      col = (int)eidx[e + E_];
    } else {
      const long long* p = (const long long*)eidx;
      row = (int)p[e];
      col = (int)p[e + E_];
    }
    unsigned pos = atomicAdd(ws + CNT_OFF + (unsigned)row, 1u);
    if (pos < 64u) {
      ws[TAB_OFF + ((unsigned)row << 6) + pos] = (unsigned)col;
    } else { // correctness-only spill
      unsigned o = atomicAdd(ws + OVFC_OFF, 1u);
      ws[OVF_OFF + 2u * o]      = (unsigned)row;
      ws[OVF_OFF + 2u * o + 1u] = (unsigned)col;
    }
  } else { // ---- W fp32 -> bf16 transposed (128 blocks)
    unsigned t = (bid - 17408u) * 256u + tid; // 0..32767
    unsigned n = t >> 7, k = t & 127u;
    ((unsigned short*)(ws + WT_OFF))[n * 128u + k] = f2bf(W[k * 256u + n]);
  }
}

// ------------ kernel 2: full-row table gather-max, packed-u16 max (bf16) --------
// R12: 81.8 -> ~55 us via v_pk_max_u16 over order-mapped x_bf. R13 cuts the two
// remaining fat issue terms:
//   * EPILOGUE SPREAD: was ~96 VALU under a g==0 EXEC mask (masked ops still
//     take issue slots). Now all 64 lanes each finish ONE u32 (channels
//     8ln+2g,+1): select mx[g]/xw[g] via 6 cndmask, one v_cvt_pk_bf16_f32
//     (hw RNE, replaces 2 f2bf+pack). ~96 masked -> ~30 all-lane.
//     Mapping proof: lane(g,ln) accumulates mx[r] for channels 8ln+2r,+1;
//     after the group-reduce, r=g matches its write slot 4ln+g exactly.
//   * deg<=24 TIER (6 loads): deg 17-32 rows loaded 32 slots for avg 20.6
//     edges; the extra tier cuts gather traffic/pkmax ~11%.
// Structure unchanged: one wave per (batch,row); 64 lanes = 4 edge-groups x 16;
// lane loads uint4 (8 ch) -> wave-load = 4 edges x full 128-ch row. Max is
// IDEMPOTENT -> clamp slot index; branch-free all-parallel gather per tier.
// EXEC discipline (R1 bug): every __shfl under wave-uniform control flow.
// batch = blockIdx&7 <-> XCD under round-robin: per-XCD x-slice is L2-sized.
__global__ __launch_bounds__(256) void k_aggr(const uint4* __restrict__ xbf4,
                                              const unsigned* __restrict__ ws,
                                              unsigned* __restrict__ aggr32) {
  const unsigned bi = blockIdx.x;            // 32768 = 4096 rowgroups x 8 batches
  const unsigned b  = bi & 7u;
  const unsigned rg = bi >> 3;               // 0..4095
  const unsigned row = (rg << 2) | (threadIdx.x >> 6); // wave <-> row
  const unsigned lane = threadIdx.x & 63u;
  const unsigned g  = lane >> 4;             // edge subgroup 0..3
  const unsigned ln = lane & 15u;            // uint4 slot within the row
  const uint4* xb = xbf4 + ((size_t)b << 18); // rows stride 16 uint4

  const unsigned deg = ws[CNT_OFF + row];    // wave-uniform (row is per-wave)
  const bool has = (deg != 0u);
  const unsigned d64 = deg < 64u ? deg : 64u;

  // issue prologue loads up front: col slots, own row (epilogue operand)
  const unsigned cpre = ws[TAB_OFF + (row << 6) + lane];
  const uint4 xw = xb[((size_t)row << 4) + ln]; // transformed; inv in epilogue

  unsigned mx[4] = {0u, 0u, 0u, 0u}; // transformed-space max (0 = below all reals)

#define MAXP(U)                                                             \
  mx[0] = pkmax(mx[0], (U).x); mx[1] = pkmax(mx[1], (U).y);                 \
  mx[2] = pkmax(mx[2], (U).z); mx[3] = pkmax(mx[3], (U).w);
#define MAXP2(U, V)                                                         \
  mx[0] = pkmax(mx[0], pkmax((U).x, (V).x));                                \
  mx[1] = pkmax(mx[1], pkmax((U).y, (V).y));                                \
  mx[2] = pkmax(mx[2], pkmax((U).z, (V).z));                                \
  mx[3] = pkmax(mx[3], pkmax((U).w, (V).w));

  if (has) { // wave-uniform
    const unsigned dm1 = d64 - 1u;
    if (d64 <= 16u) { // ---- 4 clamped loads, fully parallel (P = .57)
      unsigned c0 = (unsigned)__shfl((int)cpre, (int)umin_(g,       dm1));
      unsigned c1 = (unsigned)__shfl((int)cpre, (int)umin_(4u + g,  dm1));
      unsigned c2 = (unsigned)__shfl((int)cpre, (int)umin_(8u + g,  dm1));
      unsigned c3 = (unsigned)__shfl((int)cpre, (int)umin_(12u + g, dm1));
      uint4 u0 = xb[((size_t)c0 << 4) + ln];
      uint4 u1 = xb[((size_t)c1 << 4) + ln];
      uint4 u2 = xb[((size_t)c2 << 4) + ln];
      uint4 u3 = xb[((size_t)c3 << 4) + ln];
      MAXP2(u0, u1) MAXP2(u2, u3)
    } else if (d64 <= 24u) { // ---- 6 clamped loads (P = .30 tier)
      unsigned c[6];
#pragma unroll
      for (int i = 0; i < 6; ++i)
        c[i] = (unsigned)__shfl((int)cpre, (int)umin_(4u * i + g, dm1));
      uint4 u[6];
#pragma unroll
      for (int i = 0; i < 6; ++i) u[i] = xb[((size_t)c[i] << 4) + ln];
      MAXP2(u[0], u[1]) MAXP2(u[2], u[3]) MAXP2(u[4], u[5])
    } else if (d64 <= 32u) { // ---- 8 clamped loads (P = .12 tier)
      unsigned c[8];
#pragma unroll
      for (int i = 0; i < 8; ++i)
        c[i] = (unsigned)__shfl((int)cpre, (int)umin_(4u * i + g, dm1));
      uint4 u[8];
#pragma unroll
      for (int i = 0; i < 8; ++i) u[i] = xb[((size_t)c[i] << 4) + ln];
#pragma unroll
      for (int i = 0; i < 8; i += 2) { MAXP2(u[i], u[i + 1]) }
    } else { // ---- rare: clamped 16-chunk loop, wave-uniform trip count
      for (unsigned t = 0u; t < d64; t += 16u) {
        unsigned c0 = (unsigned)__shfl((int)cpre, (int)umin_(t + g,       dm1));
        unsigned c1 = (unsigned)__shfl((int)cpre, (int)umin_(t + 4u + g,  dm1));
        unsigned c2 = (unsigned)__shfl((int)cpre, (int)umin_(t + 8u + g,  dm1));
        unsigned c3 = (unsigned)__shfl((int)cpre, (int)umin_(t + 12u + g, dm1));
        uint4 u0 = xb[((size_t)c0 << 4) + ln];
        uint4 u1 = xb[((size_t)c1 << 4) + ln];
        uint4 u2 = xb[((size_t)c2 << 4) + ln];
        uint4 u3 = xb[((size_t)c3 << 4) + ln];
        MAXP2(u0, u1) MAXP2(u2, u3)
      }
    }
  }
  if (deg > 64u) { // overflow replay: correctness-only, shuffle-free
    unsigned no = ws[OVFC_OFF];
    for (unsigned i = 0u; i < no; i += 4u) {
      unsigned k = i + g;
      if (k < no && ws[OVF_OFF + 2u * k] == row) {
        unsigned c = ws[OVF_OFF + 2u * k + 1u];
        uint4 u = xb[((size_t)c << 4) + ln];
        MAXP(u)
      }
    }
  }
#undef MAXP
#undef MAXP2

  // reduce the 4 edge-groups (lane bits 4,5); full EXEC here (reconverged)
#pragma unroll
  for (int r = 0; r < 4; ++r)
    mx[r] = pkmax(mx[r], (unsigned)__shfl_xor((int)mx[r], 16, 64));
#pragma unroll
  for (int r = 0; r < 4; ++r)
    mx[r] = pkmax(mx[r], (unsigned)__shfl_xor((int)mx[r], 32, 64));

  // ---- epilogue, ALL lanes: each finishes u32 slot 4*ln+g (channels 8ln+2g,+1)
  {
    unsigned m0 = (g & 1u) ? mx[1] : mx[0];
    unsigned m1 = (g & 1u) ? mx[3] : mx[2];
    unsigned m  = (g & 2u) ? m1 : m0;        // this lane's channel-pair max
    unsigned x0 = (g & 1u) ? xw.y : xw.x;
    unsigned x1 = (g & 1u) ? xw.w : xw.z;
    unsigned xv = (g & 2u) ? x1 : x0;        // this lane's own-x channel pair
    m = has ? invmap(m) : 0u;                // empty row -> max := +0.0 pair
    unsigned xr = invmap(xv);
    float dlo = __uint_as_float(m << 16)        - __uint_as_float(xr << 16);
    float dhi = __uint_as_float(m & 0xFFFF0000u) - __uint_as_float(xr & 0xFFFF0000u);
    unsigned o;
    asm("v_cvt_pk_bf16_f32 %0, %1, %2" : "=v"(o) : "v"(dlo), "v"(dhi));
    aggr32[((((size_t)b << 14) + row) << 6) + (ln << 2) + g] = o;
  }
}

// ---------------- kernel 3: aggr(bf16) @ Wt(bf16) + b, fast GELU ----------------
// R3-structure gemm + gelu_fast (R10-verified) + nontemporal out stores.
// Near HBM roofline (out 134 MB + aggr 33.5 ~ 26 us floor vs ~30 actual).
__global__ __launch_bounds__(256, 4) void k_gemm(const unsigned short* __restrict__ aggr,
                                                 const unsigned short* __restrict__ Wt,
                                                 const float* __restrict__ bias,
                                                 float* __restrict__ out) {
  __shared__ unsigned short Wt_sm[128 * 136]; // 34816 B; stride 136 (2-way free)
  const int tid = threadIdx.x;
  const int nbase = blockIdx.x * 128; // n-tiles adjacent in dispatch: A re-read
  const int mbase = blockIdx.y * 64;  // of the same m-tile stays cache-warm

#pragma unroll
  for (int i = 0; i < 8; ++i) {
    int slot = i * 256 + tid;
    int n = slot >> 4, k8 = slot & 15;
    uint4 u = *(const uint4*)(Wt + (size_t)(nbase + n) * 128 + k8 * 8);
    *(uint4*)&Wt_sm[n * 136 + k8 * 8] = u;
  }
  __syncthreads();

  const int lane = tid & 63;
  const int wv = tid >> 6;   // wave id: rows [wv*16, wv*16+16)
  const int ln = lane & 15;
  const int q = lane >> 4;   // quad

  // A-operand: A[m = lane&15][k = quad*8 + j] -> 16B contiguous in global
  const unsigned short* arow = aggr + (size_t)(mbase + wv * 16 + ln) * 128 + q * 8;
  bf16x8 af[4];
#pragma unroll
  for (int kc = 0; kc < 4; ++kc) af[kc] = *(const bf16x8*)(arow + kc * 32);

  f32x4 acc[8];
#pragma unroll
  for (int f = 0; f < 8; ++f) acc[f] = (f32x4){0.f, 0.f, 0.f, 0.f};

#pragma unroll
  for (int kc = 0; kc < 4; ++kc) {
#pragma unroll
    for (int f = 0; f < 8; ++f) {
      // B-operand: B[k = quad*8 + j][n = lane&15] contiguous in Wt[n][k]
      bf16x8 bf = *(const bf16x8*)&Wt_sm[(f * 16 + ln) * 136 + kc * 32 + q * 8];
      acc[f] = __builtin_amdgcn_mfma_f32_16x16x32_bf16(af[kc], bf, acc[f], 0, 0, 0);
    }
  }

  // Epilogue: C/D layout col = lane&15, row = quad*4 + reg (m89-verified)
#pragma unroll
  for (int f = 0; f < 8; ++f) {
    int n = nbase + f * 16 + ln;
    float bv = bias[n];
#pragma unroll
    for (int r = 0; r < 4; ++r) {
      int m = mbase + wv * 16 + q * 4 + r;
      __builtin_nontemporal_store(gelu_fast(acc[f][r] + bv),
                                  &out[(size_t)m * 256 + n]);
    }
  }
}

extern "C" void kernel_launch(void* const* d_in, const int* in_sizes, int n_in,
                              void* d_out, int out_size, void* d_ws, size_t ws_size,
                              hipStream_t stream) {
  const float* x      = (const float*)d_in[0];
  const unsigned* eid = (const unsigned*)d_in[1];
  const float* W      = (const float*)d_in[2];
  const float* bia    = (const float*)d_in[3];
  float* out          = (float*)d_out;
  unsigned* ws        = (unsigned*)d_ws;

  unsigned short* Wt   = (unsigned short*)(ws + WT_OFF);
  unsigned short* aggr = (unsigned short*)(ws + AGGR_OFF);

  // zero cnt[16384] + ovf_cnt (+pad)
  hipMemsetAsync(ws + CNT_OFF, 0, 16448 * sizeof(unsigned), stream);
  hipLaunchKernelGGL(k_prep, dim3(17536),   dim3(256), 0, stream, x, eid, W, ws);
  hipLaunchKernelGGL(k_aggr, dim3(32768),   dim3(256), 0, stream,
                     (const uint4*)(ws + XBF_OFF), ws, ws + AGGR_OFF);
  hipLaunchKernelGGL(k_gemm, dim3(2, 2048), dim3(256), 0, stream,
                     aggr, Wt, bia, out);
}